// Round 6
// baseline (496.712 us; speedup 1.0000x reference)
//
#include <hip/hip_runtime.h>
#include <math.h>

// CapsNet dynamic routing, fp32 — streaming sweeps with explicit software pipeline.
//
// R5 -> R6: R5 sweeps hit VALUBusy 47% at Occupancy 33% — grid (512 x 8-wave
// blocks) left CUs half-empty; resources allowed more (VGPR 60, LDS 34.8KB).
// This round: 16-wave blocks (1024 thr), launch_bounds(1024,8) -> 2 blocks/CU
// = 32 waves/CU (cap). Pipeline, P-buffers, ws layout identical to R5.
//
// x: [B=64, N=1152, Din=8], W: [C=128, N=1152, Din=8, Dout=16]
// out: [B=64, C=128, Dout=16]

constexpr int NCAP = 1152;
constexpr int DIN  = 8;
constexpr int DOUT = 16;
constexpr int NCLS = 128;
constexpr int NB   = 64;

constexpr int CH        = 4;                  // n-chunks (blocks) per class
constexpr int NW        = 16;                 // waves per sweep block
constexpr int SWEEP_BLK = NW * 64;            // 1024 threads
constexpr int NPC       = NCAP / CH;          // 288 rows per block
constexpr int NPW       = NPC / NW;           // 18 rows per wave
constexpr int NPAIRS    = NPW / 2;            // 9 row-pairs per wave
constexpr int STG       = 4096;               // per-wave staging: 4 bufs x 1KB
constexpr int ROW_BYTES = DIN * DOUT * 4;     // 512 B per W row

// ws layout (float offsets) — same as R4/R5
constexpr size_t XS_OFF = 0;
constexpr size_t XS_SZ  = (size_t)NCAP * NB * DIN;               // 589,824
constexpr size_t P1_OFF = XS_OFF + XS_SZ;
constexpr size_t P1_SZ  = (size_t)NCLS * CH * DOUT * NB;         // 524,288
constexpr size_t P2_OFF = P1_OFF + P1_SZ;
constexpr size_t P23_SZ = (size_t)NCLS * CH * (DOUT + 1) * NB;   // 557,056
constexpr size_t P3_OFF = P2_OFF + P23_SZ;                       // total ~8.9 MB

#define WAITV(N) asm volatile("s_waitcnt vmcnt(" #N ")" ::: "memory")
#define SB() __builtin_amdgcn_sched_barrier(0)

// ---- prep: squash(x) and transpose to xs[n][b][0..7]
__global__ __launch_bounds__(256) void prep_kernel(const float* __restrict__ x,
                                                   float* __restrict__ xs) {
    const int g = blockIdx.x * 256 + threadIdx.x;   // g = n*64 + b
    const int n = g >> 6;
    const int b = g & 63;
    const float4* xp = reinterpret_cast<const float4*>(x + ((size_t)b * NCAP + n) * DIN);
    float4 a = xp[0], c4 = xp[1];
    float sq = a.x*a.x + a.y*a.y + a.z*a.z + a.w*a.w
             + c4.x*c4.x + c4.y*c4.y + c4.z*c4.z + c4.w*c4.w;
    float sc = sq / ((1.0f + sq) * sqrtf(sq));
    float4 o0 = {a.x*sc,  a.y*sc,  a.z*sc,  a.w*sc};
    float4 o1 = {c4.x*sc, c4.y*sc, c4.z*sc, c4.w*sc};
    float4* op = reinterpret_cast<float4*>(xs + (size_t)g * DIN);
    op[0] = o0;
    op[1] = o1;
}

// ---- sweep: one streaming pass over this block's n-range.
// PHASE 1: b=0 -> uniform coupling: S = sum_n u_n   (Z unused)
// PHASE 2: V = v1;       Z = sum exp(u.V), S = sum exp(u.V) u
// PHASE 3: V = v1+v2;    same accumulation, written to P3
template<int PHASE>
__global__ __launch_bounds__(SWEEP_BLK, 8) void sweep_kernel(const float* __restrict__ xs,
                                                             const float* __restrict__ W,
                                                             float* __restrict__ ws) {
    const int c  = blockIdx.x >> 2;      // 0..127
    const int ch = blockIdx.x & 3;       // 0..3
    const int b  = threadIdx.x & 63;     // lane = batch
    const int w  = threadIdx.x >> 6;     // wave id 0..15

    // union: staging (16 waves x 4KB = 64KB) then reduction (16x17x64x4 = 69.6KB)
    __shared__ __align__(16) char smem[NW * (DOUT + 1) * NB * 4];

    float* P1 = ws + P1_OFF;
    float* P2 = ws + P2_OFF;
    float* P3 = ws + P3_OFF;

    // prologue: reconstruct V = sum of previous v's for (c, b)
    float V[DOUT];
    if (PHASE >= 2) {
        float sq = 0.f;
#pragma unroll
        for (int o = 0; o < DOUT; ++o) {
            float acc = 0.f;
#pragma unroll
            for (int k = 0; k < CH; ++k)
                acc += P1[(((size_t)c * CH + k) * DOUT + o) * NB + b];
            acc *= (1.0f / (float)NCAP);          // uniform c = 1/N
            V[o] = acc;
            sq += acc * acc;
        }
        const float sc = sq / ((1.0f + sq) * sqrtf(sq));
#pragma unroll
        for (int o = 0; o < DOUT; ++o) V[o] *= sc;   // V = v1
        if (PHASE == 3) {
            float Z2 = 0.f;
#pragma unroll
            for (int k = 0; k < CH; ++k)
                Z2 += P2[(((size_t)c * CH + k) * (DOUT + 1) + DOUT) * NB + b];
            const float rz = 1.0f / Z2;
            float s2[DOUT];
            float sq2 = 0.f;
#pragma unroll
            for (int o = 0; o < DOUT; ++o) {
                float acc = 0.f;
#pragma unroll
                for (int k = 0; k < CH; ++k)
                    acc += P2[(((size_t)c * CH + k) * (DOUT + 1) + o) * NB + b];
                acc *= rz;
                s2[o] = acc;
                sq2 += acc * acc;
            }
            const float sc2 = sq2 / ((1.0f + sq2) * sqrtf(sq2));
#pragma unroll
            for (int o = 0; o < DOUT; ++o) V[o] += s2[o] * sc2;  // V = v1+v2
        }
    }

    float S[DOUT];
#pragma unroll
    for (int o = 0; o < DOUT; ++o) S[o] = 0.f;
    float Z = 0.f;

    const int n0 = ch * NPC + w * NPW;
    const char* wsrc = (const char*)W + ((size_t)c * NCAP + n0) * ROW_BYTES;
    char* mybuf = smem + w * STG;

    // stage pair p (2 rows = 1KB): lane b loads 16B into mybuf[(p&3)*1024 + b*16]
    auto STAGE = [&](int p) {
        __builtin_amdgcn_global_load_lds(
            (const __attribute__((address_space(1))) void*)(wsrc + (size_t)p * 1024 + b * 16),
            (__attribute__((address_space(3))) void*)(mybuf + (p & 3) * 1024),
            16, 0, 0);
    };
    auto XROW = [&](int row, float4& xa, float4& xb) {
        const float4* xp = reinterpret_cast<const float4*>(
            xs + ((size_t)(n0 + row) * NB + b) * DIN);
        xa = xp[0];
        xb = xp[1];
    };
    auto ROW = [&](int p, int r, float4 xa, float4 xb) {
        const float4* wl = reinterpret_cast<const float4*>(mybuf + (p & 3) * 1024 + r * 512);
        const float xv[DIN] = {xa.x, xa.y, xa.z, xa.w, xb.x, xb.y, xb.z, xb.w};
        if (PHASE == 1) {
#pragma unroll
            for (int i = 0; i < DIN; ++i) {
                float4 q0 = wl[i*4+0], q1 = wl[i*4+1], q2 = wl[i*4+2], q3 = wl[i*4+3];
                const float xi = xv[i];
                S[ 0]=fmaf(xi,q0.x,S[ 0]); S[ 1]=fmaf(xi,q0.y,S[ 1]);
                S[ 2]=fmaf(xi,q0.z,S[ 2]); S[ 3]=fmaf(xi,q0.w,S[ 3]);
                S[ 4]=fmaf(xi,q1.x,S[ 4]); S[ 5]=fmaf(xi,q1.y,S[ 5]);
                S[ 6]=fmaf(xi,q1.z,S[ 6]); S[ 7]=fmaf(xi,q1.w,S[ 7]);
                S[ 8]=fmaf(xi,q2.x,S[ 8]); S[ 9]=fmaf(xi,q2.y,S[ 9]);
                S[10]=fmaf(xi,q2.z,S[10]); S[11]=fmaf(xi,q2.w,S[11]);
                S[12]=fmaf(xi,q3.x,S[12]); S[13]=fmaf(xi,q3.y,S[13]);
                S[14]=fmaf(xi,q3.z,S[14]); S[15]=fmaf(xi,q3.w,S[15]);
            }
        } else {
            float u[DOUT];
#pragma unroll
            for (int o = 0; o < DOUT; ++o) u[o] = 0.f;
#pragma unroll
            for (int i = 0; i < DIN; ++i) {
                float4 q0 = wl[i*4+0], q1 = wl[i*4+1], q2 = wl[i*4+2], q3 = wl[i*4+3];
                const float xi = xv[i];
                u[ 0]=fmaf(xi,q0.x,u[ 0]); u[ 1]=fmaf(xi,q0.y,u[ 1]);
                u[ 2]=fmaf(xi,q0.z,u[ 2]); u[ 3]=fmaf(xi,q0.w,u[ 3]);
                u[ 4]=fmaf(xi,q1.x,u[ 4]); u[ 5]=fmaf(xi,q1.y,u[ 5]);
                u[ 6]=fmaf(xi,q1.z,u[ 6]); u[ 7]=fmaf(xi,q1.w,u[ 7]);
                u[ 8]=fmaf(xi,q2.x,u[ 8]); u[ 9]=fmaf(xi,q2.y,u[ 9]);
                u[10]=fmaf(xi,q2.z,u[10]); u[11]=fmaf(xi,q2.w,u[11]);
                u[12]=fmaf(xi,q3.x,u[12]); u[13]=fmaf(xi,q3.y,u[13]);
                u[14]=fmaf(xi,q3.z,u[14]); u[15]=fmaf(xi,q3.w,u[15]);
            }
            float bd = 0.f;
#pragma unroll
            for (int o = 0; o < DOUT; ++o) bd = fmaf(u[o], V[o], bd);
            const float g = __expf(bd);   // |bd| <= ~48: fp32-safe, no max-sub
            Z += g;
#pragma unroll
            for (int o = 0; o < DOUT; ++o) S[o] = fmaf(g, u[o], S[o]);
        }
    };

    // ---- software pipeline: W staged 2 pairs ahead, xs 1 pair ahead.
    // FIFO per iter p: [STAGE(p+2)] [XROW(p+1) x4]. Steady-state wait = vmcnt(5).
    STAGE(0); SB();
    STAGE(1); SB();
    float4 ca0, ca1, cb0, cb1, na0, na1, nb0, nb1;
    XROW(0, ca0, ca1);
    XROW(1, cb0, cb1);
    SB();

#pragma unroll 1
    for (int p = 0; p < NPAIRS; ++p) {
        if (p + 2 < NPAIRS) STAGE(p + 2);
        SB();
        if (p + 1 < NPAIRS) {
            XROW(2 * (p + 1),     na0, na1);
            XROW(2 * (p + 1) + 1, nb0, nb1);
        }
        SB();
        if (p < NPAIRS - 2)       { WAITV(5); }
        else if (p == NPAIRS - 2) { WAITV(4); }
        else                      { WAITV(0); }
        SB();
        ROW(p, 0, ca0, ca1);
        ROW(p, 1, cb0, cb1);
        ca0 = na0; ca1 = na1; cb0 = nb0; cb1 = nb1;
    }

    // ---- cross-wave merge (reuse smem after all waves finish staging reads)
    __syncthreads();
    float (*red)[DOUT + 1][NB] = reinterpret_cast<float (*)[DOUT + 1][NB]>(smem);
#pragma unroll
    for (int o = 0; o < DOUT; ++o) red[w][o][b] = S[o];
    red[w][DOUT][b] = Z;
    __syncthreads();
    for (int idx = threadIdx.x; idx < (DOUT + 1) * NB; idx += SWEEP_BLK) {
        const int slot = idx >> 6;
        const int bb   = idx & 63;
        float acc = 0.f;
#pragma unroll
        for (int k = 0; k < NW; ++k) acc += red[k][slot][bb];
        if (PHASE == 1) {
            if (slot < DOUT)
                P1[(((size_t)c * CH + ch) * DOUT + slot) * NB + bb] = acc;
        } else {
            float* P = (PHASE == 2) ? P2 : P3;
            P[(((size_t)c * CH + ch) * (DOUT + 1) + slot) * NB + bb] = acc;
        }
    }
}

// ---- final: merge P3 -> v3, leaky^2, per-batch normalize, write out[b,c,o]
__global__ __launch_bounds__(256) void final_kernel(const float* __restrict__ ws_ro,
                                                    float* __restrict__ out) {
    const float* P3 = ws_ro + P3_OFF;
    const int b    = blockIdx.x;
    const int tid  = threadIdx.x;
    const int c    = tid >> 1;
    const int half = tid & 1;   // 8 of 16 Dout elements each

    float Zt = 0.f;
#pragma unroll
    for (int k = 0; k < CH; ++k)
        Zt += P3[(((size_t)c * CH + k) * (DOUT + 1) + DOUT) * NB + b];
    const float rz = 1.0f / Zt;

    float s[8];
    float sqh = 0.f;
#pragma unroll
    for (int j = 0; j < 8; ++j) {
        const int o = half * 8 + j;
        float acc = 0.f;
#pragma unroll
        for (int k = 0; k < CH; ++k)
            acc += P3[(((size_t)c * CH + k) * (DOUT + 1) + o) * NB + b];
        acc *= rz;
        s[j] = acc;
        sqh += acc * acc;
    }
    const float sq = sqh + __shfl_xor(sqh, 1);
    const float sc = sq / ((1.0f + sq) * sqrtf(sq));

    float val[8];
    float ps = 0.f;
#pragma unroll
    for (int j = 0; j < 8; ++j) {
        const float v = s[j] * sc;
        const float l = v > 0.f ? v : 0.01f * v;
        val[j] = l * l;
        ps += val[j];
    }
#pragma unroll
    for (int off = 1; off < 64; off <<= 1) ps += __shfl_xor(ps, off);
    __shared__ float wsum[4];
    if ((tid & 63) == 0) wsum[tid >> 6] = ps;
    __syncthreads();
    const float inv = 1.0f / (wsum[0] + wsum[1] + wsum[2] + wsum[3]);
#pragma unroll
    for (int j = 0; j < 8; ++j)
        out[((size_t)b * NCLS + c) * DOUT + half * 8 + j] = val[j] * inv;
}

extern "C" void kernel_launch(void* const* d_in, const int* in_sizes, int n_in,
                              void* d_out, int out_size, void* d_ws, size_t ws_size,
                              hipStream_t stream) {
    const float* x = (const float*)d_in[0];
    const float* W = (const float*)d_in[1];
    float* out = (float*)d_out;
    float* ws  = (float*)d_ws;

    hipLaunchKernelGGL(prep_kernel, dim3(NCAP * NB / 256), dim3(256), 0, stream,
                       x, ws + XS_OFF);
    hipLaunchKernelGGL((sweep_kernel<1>), dim3(NCLS * CH), dim3(SWEEP_BLK), 0, stream,
                       ws + XS_OFF, W, ws);
    hipLaunchKernelGGL((sweep_kernel<2>), dim3(NCLS * CH), dim3(SWEEP_BLK), 0, stream,
                       ws + XS_OFF, W, ws);
    hipLaunchKernelGGL((sweep_kernel<3>), dim3(NCLS * CH), dim3(SWEEP_BLK), 0, stream,
                       ws + XS_OFF, W, ws);
    hipLaunchKernelGGL(final_kernel, dim3(NB), dim3(256), 0, stream, ws, out);
}

// Round 7
// 494.601 us; speedup vs baseline: 1.0043x; 1.0043x over previous
//
#include <hip/hip_runtime.h>
#include <math.h>

// CapsNet dynamic routing, fp32 — streaming sweeps, packed-fp32 + higher residency.
//
// R6 post-mortem: launch_bounds(1024,8) => 64-VGPR cap => spill catastrophe.
// R7: back to R5's proven 8-wave pipeline, plus:
//  (a) v_pk_fma_f32 via ext_vector_type(4) + __builtin_elementwise_fma
//      (fp32 peak is packed; scalar fmaf leaves 2x issue on the table)
//  (b) CH=8 (1024 blocks, 18 rows/wave) with launch_bounds(512,6) -> ~84 VGPR
//      cap, 3 blocks/CU. ws grows to 15.5MB — runtime-guarded by ws_size with
//      CH=4 fallback.
//
// x: [B=64, N=1152, Din=8], W: [C=128, N=1152, Din=8, Dout=16]
// out: [B=64, C=128, Dout=16]

typedef float f32x4 __attribute__((ext_vector_type(4)));

constexpr int NCAP = 1152;
constexpr int DIN  = 8;
constexpr int DOUT = 16;
constexpr int NCLS = 128;
constexpr int NB   = 64;

constexpr int NW        = 8;                  // waves per sweep block
constexpr int SWEEP_BLK = NW * 64;            // 512 threads
constexpr int STG       = 4096;               // per-wave staging: 4 bufs x 1KB
constexpr int ROW_BYTES = DIN * DOUT * 4;     // 512 B per W row

template<int CH> struct Layout {
    static constexpr size_t XS_OFF = 0;
    static constexpr size_t XS_SZ  = (size_t)NCAP * NB * DIN;
    static constexpr size_t P1_OFF = XS_OFF + XS_SZ;
    static constexpr size_t P1_SZ  = (size_t)NCLS * CH * DOUT * NB;
    static constexpr size_t P2_OFF = P1_OFF + P1_SZ;
    static constexpr size_t P23_SZ = (size_t)NCLS * CH * (DOUT + 1) * NB;
    static constexpr size_t P3_OFF = P2_OFF + P23_SZ;
    static constexpr size_t TOTAL  = P3_OFF + P23_SZ;   // floats
};

#define WAITV(N) asm volatile("s_waitcnt vmcnt(" #N ")" ::: "memory")
#define SB() __builtin_amdgcn_sched_barrier(0)

// ---- prep: squash(x) and transpose to xs[n][b][0..7]
__global__ __launch_bounds__(256) void prep_kernel(const float* __restrict__ x,
                                                   float* __restrict__ xs) {
    const int g = blockIdx.x * 256 + threadIdx.x;   // g = n*64 + b
    const int n = g >> 6;
    const int b = g & 63;
    const float4* xp = reinterpret_cast<const float4*>(x + ((size_t)b * NCAP + n) * DIN);
    float4 a = xp[0], c4 = xp[1];
    float sq = a.x*a.x + a.y*a.y + a.z*a.z + a.w*a.w
             + c4.x*c4.x + c4.y*c4.y + c4.z*c4.z + c4.w*c4.w;
    float sc = sq / ((1.0f + sq) * sqrtf(sq));
    float4 o0 = {a.x*sc,  a.y*sc,  a.z*sc,  a.w*sc};
    float4 o1 = {c4.x*sc, c4.y*sc, c4.z*sc, c4.w*sc};
    float4* op = reinterpret_cast<float4*>(xs + (size_t)g * DIN);
    op[0] = o0;
    op[1] = o1;
}

// ---- sweep: one streaming pass over this block's n-range.
// PHASE 1: b=0 -> uniform coupling: S = sum_n u_n   (Z unused)
// PHASE 2: V = v1;       Z = sum exp(u.V), S = sum exp(u.V) u
// PHASE 3: V = v1+v2;    same accumulation, written to P3
template<int PHASE, int CH>
__global__ __launch_bounds__(SWEEP_BLK, 6) void sweep_kernel(const float* __restrict__ xs,
                                                             const float* __restrict__ W,
                                                             float* __restrict__ ws) {
    constexpr int NPC    = NCAP / CH;    // rows per block
    constexpr int NPW    = NPC / NW;     // rows per wave
    constexpr int NPAIRS = NPW / 2;      // row-pairs per wave
    using L = Layout<CH>;

    const int c  = blockIdx.x / CH;
    const int ch = blockIdx.x % CH;
    const int b  = threadIdx.x & 63;     // lane = batch
    const int w  = threadIdx.x >> 6;     // wave id

    // union: staging (8 waves x 4KB = 32KB) then reduction (8x17x64x4 = 34.8KB)
    __shared__ __align__(16) char smem[NW * (DOUT + 1) * NB * 4];

    float* P1 = ws + L::P1_OFF;
    float* P2 = ws + L::P2_OFF;
    float* P3 = ws + L::P3_OFF;

    // prologue: reconstruct V = sum of previous v's for (c, b)  (cold, scalar)
    f32x4 V4[4];
    if (PHASE >= 2) {
        float V[DOUT];
        float sq = 0.f;
#pragma unroll
        for (int o = 0; o < DOUT; ++o) {
            float acc = 0.f;
#pragma unroll
            for (int k = 0; k < CH; ++k)
                acc += P1[(((size_t)c * CH + k) * DOUT + o) * NB + b];
            acc *= (1.0f / (float)NCAP);          // uniform c = 1/N
            V[o] = acc;
            sq += acc * acc;
        }
        const float sc = sq / ((1.0f + sq) * sqrtf(sq));
#pragma unroll
        for (int o = 0; o < DOUT; ++o) V[o] *= sc;   // V = v1
        if (PHASE == 3) {
            float Z2 = 0.f;
#pragma unroll
            for (int k = 0; k < CH; ++k)
                Z2 += P2[(((size_t)c * CH + k) * (DOUT + 1) + DOUT) * NB + b];
            const float rz = 1.0f / Z2;
            float s2[DOUT];
            float sq2 = 0.f;
#pragma unroll
            for (int o = 0; o < DOUT; ++o) {
                float acc = 0.f;
#pragma unroll
                for (int k = 0; k < CH; ++k)
                    acc += P2[(((size_t)c * CH + k) * (DOUT + 1) + o) * NB + b];
                acc *= rz;
                s2[o] = acc;
                sq2 += acc * acc;
            }
            const float sc2 = sq2 / ((1.0f + sq2) * sqrtf(sq2));
#pragma unroll
            for (int o = 0; o < DOUT; ++o) V[o] += s2[o] * sc2;  // V = v1+v2
        }
#pragma unroll
        for (int j = 0; j < 4; ++j)
            V4[j] = (f32x4){V[4*j], V[4*j+1], V[4*j+2], V[4*j+3]};
    }

    f32x4 S4[4];
#pragma unroll
    for (int j = 0; j < 4; ++j) S4[j] = (f32x4){0.f, 0.f, 0.f, 0.f};
    float Z = 0.f;

    const int n0 = ch * NPC + w * NPW;
    const char* wsrc = (const char*)W + ((size_t)c * NCAP + n0) * ROW_BYTES;
    char* mybuf = smem + w * STG;

    // stage pair p (2 rows = 1KB): lane b loads 16B into mybuf[(p&3)*1024 + b*16]
    auto STAGE = [&](int p) {
        __builtin_amdgcn_global_load_lds(
            (const __attribute__((address_space(1))) void*)(wsrc + (size_t)p * 1024 + b * 16),
            (__attribute__((address_space(3))) void*)(mybuf + (p & 3) * 1024),
            16, 0, 0);
    };
    auto XROW = [&](int row, float4& xa, float4& xb) {
        const float4* xp = reinterpret_cast<const float4*>(
            xs + ((size_t)(n0 + row) * NB + b) * DIN);
        xa = xp[0];
        xb = xp[1];
    };
    auto ROW = [&](int p, int r, float4 xa, float4 xb) {
        const f32x4* wl = reinterpret_cast<const f32x4*>(mybuf + (p & 3) * 1024 + r * 512);
        const float xv[DIN] = {xa.x, xa.y, xa.z, xa.w, xb.x, xb.y, xb.z, xb.w};
        if (PHASE == 1) {
#pragma unroll
            for (int i = 0; i < DIN; ++i) {
                const f32x4 xi = {xv[i], xv[i], xv[i], xv[i]};
#pragma unroll
                for (int j = 0; j < 4; ++j)
                    S4[j] = __builtin_elementwise_fma(xi, wl[i*4+j], S4[j]);
            }
        } else {
            f32x4 u0 = {0.f,0.f,0.f,0.f}, u1 = u0, u2 = u0, u3 = u0;
#pragma unroll
            for (int i = 0; i < DIN; ++i) {
                const f32x4 xi = {xv[i], xv[i], xv[i], xv[i]};
                u0 = __builtin_elementwise_fma(xi, wl[i*4+0], u0);
                u1 = __builtin_elementwise_fma(xi, wl[i*4+1], u1);
                u2 = __builtin_elementwise_fma(xi, wl[i*4+2], u2);
                u3 = __builtin_elementwise_fma(xi, wl[i*4+3], u3);
            }
            f32x4 d4 = u0 * V4[0];
            d4 = __builtin_elementwise_fma(u1, V4[1], d4);
            d4 = __builtin_elementwise_fma(u2, V4[2], d4);
            d4 = __builtin_elementwise_fma(u3, V4[3], d4);
            const float bd = (d4.x + d4.y) + (d4.z + d4.w);
            const float g = __expf(bd);   // |bd| <= ~48: fp32-safe, no max-sub
            Z += g;
            const f32x4 g4 = {g, g, g, g};
            S4[0] = __builtin_elementwise_fma(g4, u0, S4[0]);
            S4[1] = __builtin_elementwise_fma(g4, u1, S4[1]);
            S4[2] = __builtin_elementwise_fma(g4, u2, S4[2]);
            S4[3] = __builtin_elementwise_fma(g4, u3, S4[3]);
        }
    };

    // ---- software pipeline: W staged 2 pairs ahead, xs 1 pair ahead.
    // FIFO per iter p: [STAGE(p+2)] [XROW(p+1) x4]. Steady-state wait = vmcnt(5).
    STAGE(0); SB();
    STAGE(1); SB();
    float4 ca0, ca1, cb0, cb1, na0, na1, nb0, nb1;
    XROW(0, ca0, ca1);
    XROW(1, cb0, cb1);
    SB();

#pragma unroll 1
    for (int p = 0; p < NPAIRS; ++p) {
        if (p + 2 < NPAIRS) STAGE(p + 2);
        SB();
        if (p + 1 < NPAIRS) {
            XROW(2 * (p + 1),     na0, na1);
            XROW(2 * (p + 1) + 1, nb0, nb1);
        }
        SB();
        if (p < NPAIRS - 2)       { WAITV(5); }
        else if (p == NPAIRS - 2) { WAITV(4); }
        else                      { WAITV(0); }
        SB();
        ROW(p, 0, ca0, ca1);
        ROW(p, 1, cb0, cb1);
        ca0 = na0; ca1 = na1; cb0 = nb0; cb1 = nb1;
    }

    // ---- cross-wave merge (reuse smem after all waves finish staging reads)
    __syncthreads();
    float (*red)[DOUT + 1][NB] = reinterpret_cast<float (*)[DOUT + 1][NB]>(smem);
#pragma unroll
    for (int o = 0; o < DOUT; ++o) red[w][o][b] = S4[o / 4][o % 4];
    red[w][DOUT][b] = Z;
    __syncthreads();
    for (int idx = threadIdx.x; idx < (DOUT + 1) * NB; idx += SWEEP_BLK) {
        const int slot = idx >> 6;
        const int bb   = idx & 63;
        float acc = 0.f;
#pragma unroll
        for (int k = 0; k < NW; ++k) acc += red[k][slot][bb];
        if (PHASE == 1) {
            if (slot < DOUT)
                P1[(((size_t)c * CH + ch) * DOUT + slot) * NB + bb] = acc;
        } else {
            float* P = (PHASE == 2) ? P2 : P3;
            P[(((size_t)c * CH + ch) * (DOUT + 1) + slot) * NB + bb] = acc;
        }
    }
}

// ---- final: merge P3 -> v3, leaky^2, per-batch normalize, write out[b,c,o]
template<int CH>
__global__ __launch_bounds__(256) void final_kernel(const float* __restrict__ ws_ro,
                                                    float* __restrict__ out) {
    using L = Layout<CH>;
    const float* P3 = ws_ro + L::P3_OFF;
    const int b    = blockIdx.x;
    const int tid  = threadIdx.x;
    const int c    = tid >> 1;
    const int half = tid & 1;   // 8 of 16 Dout elements each

    float Zt = 0.f;
#pragma unroll
    for (int k = 0; k < CH; ++k)
        Zt += P3[(((size_t)c * CH + k) * (DOUT + 1) + DOUT) * NB + b];
    const float rz = 1.0f / Zt;

    float s[8];
    float sqh = 0.f;
#pragma unroll
    for (int j = 0; j < 8; ++j) {
        const int o = half * 8 + j;
        float acc = 0.f;
#pragma unroll
        for (int k = 0; k < CH; ++k)
            acc += P3[(((size_t)c * CH + k) * (DOUT + 1) + o) * NB + b];
        acc *= rz;
        s[j] = acc;
        sqh += acc * acc;
    }
    const float sq = sqh + __shfl_xor(sqh, 1);
    const float sc = sq / ((1.0f + sq) * sqrtf(sq));

    float val[8];
    float ps = 0.f;
#pragma unroll
    for (int j = 0; j < 8; ++j) {
        const float v = s[j] * sc;
        const float l = v > 0.f ? v : 0.01f * v;
        val[j] = l * l;
        ps += val[j];
    }
#pragma unroll
    for (int off = 1; off < 64; off <<= 1) ps += __shfl_xor(ps, off);
    __shared__ float wsum[4];
    if ((tid & 63) == 0) wsum[tid >> 6] = ps;
    __syncthreads();
    const float inv = 1.0f / (wsum[0] + wsum[1] + wsum[2] + wsum[3]);
#pragma unroll
    for (int j = 0; j < 8; ++j)
        out[((size_t)b * NCLS + c) * DOUT + half * 8 + j] = val[j] * inv;
}

extern "C" void kernel_launch(void* const* d_in, const int* in_sizes, int n_in,
                              void* d_out, int out_size, void* d_ws, size_t ws_size,
                              hipStream_t stream) {
    const float* x = (const float*)d_in[0];
    const float* W = (const float*)d_in[1];
    float* out = (float*)d_out;
    float* ws  = (float*)d_ws;

    hipLaunchKernelGGL(prep_kernel, dim3(NCAP * NB / 256), dim3(256), 0, stream,
                       x, ws);

    if (ws_size >= Layout<8>::TOTAL * sizeof(float)) {
        hipLaunchKernelGGL((sweep_kernel<1, 8>), dim3(NCLS * 8), dim3(SWEEP_BLK), 0, stream,
                           ws, W, ws);
        hipLaunchKernelGGL((sweep_kernel<2, 8>), dim3(NCLS * 8), dim3(SWEEP_BLK), 0, stream,
                           ws, W, ws);
        hipLaunchKernelGGL((sweep_kernel<3, 8>), dim3(NCLS * 8), dim3(SWEEP_BLK), 0, stream,
                           ws, W, ws);
        hipLaunchKernelGGL((final_kernel<8>), dim3(NB), dim3(256), 0, stream, ws, out);
    } else {
        hipLaunchKernelGGL((sweep_kernel<1, 4>), dim3(NCLS * 4), dim3(SWEEP_BLK), 0, stream,
                           ws, W, ws);
        hipLaunchKernelGGL((sweep_kernel<2, 4>), dim3(NCLS * 4), dim3(SWEEP_BLK), 0, stream,
                           ws, W, ws);
        hipLaunchKernelGGL((sweep_kernel<3, 4>), dim3(NCLS * 4), dim3(SWEEP_BLK), 0, stream,
                           ws, W, ws);
        hipLaunchKernelGGL((final_kernel<4>), dim3(NB), dim3(256), 0, stream, ws, out);
    }
}

// Round 8
// 198.950 us; speedup vs baseline: 2.4967x; 2.4861x over previous
//
#include <hip/hip_runtime.h>
#include <math.h>

// CapsNet dynamic routing, fp32 — streaming sweeps with explicit software pipeline.
//
// R7 post-mortem: packed-fp32 rewrite + launch_bounds(512,6) spilled (VGPR 40,
// 476MB scratch writes/sweep). R8 = exact R5 body (proven 60 VGPR, no spill)
// with ONE change: CH 4->8 (512->1024 blocks) so occupancy goes from
// grid-limited 2 blocks/CU to the resource limit 4 blocks/CU (VGPR 60<=64,
// LDS 34.8KB x4 = 139KB <= 160KB). ws 15.5MB, guarded, CH=4 fallback.
//
// x: [B=64, N=1152, Din=8], W: [C=128, N=1152, Din=8, Dout=16]
// out: [B=64, C=128, Dout=16]

constexpr int NCAP = 1152;
constexpr int DIN  = 8;
constexpr int DOUT = 16;
constexpr int NCLS = 128;
constexpr int NB   = 64;

constexpr int NW        = 8;                  // waves per sweep block
constexpr int SWEEP_BLK = NW * 64;            // 512 threads
constexpr int STG       = 4096;               // per-wave staging: 4 bufs x 1KB
constexpr int ROW_BYTES = DIN * DOUT * 4;     // 512 B per W row

template<int CH> struct Layout {
    static constexpr size_t XS_OFF = 0;
    static constexpr size_t XS_SZ  = (size_t)NCAP * NB * DIN;
    static constexpr size_t P1_OFF = XS_OFF + XS_SZ;
    static constexpr size_t P1_SZ  = (size_t)NCLS * CH * DOUT * NB;
    static constexpr size_t P2_OFF = P1_OFF + P1_SZ;
    static constexpr size_t P23_SZ = (size_t)NCLS * CH * (DOUT + 1) * NB;
    static constexpr size_t P3_OFF = P2_OFF + P23_SZ;
    static constexpr size_t TOTAL  = P3_OFF + P23_SZ;   // floats
};

#define WAITV(N) asm volatile("s_waitcnt vmcnt(" #N ")" ::: "memory")
#define SB() __builtin_amdgcn_sched_barrier(0)

// ---- prep: squash(x) and transpose to xs[n][b][0..7]
__global__ __launch_bounds__(256) void prep_kernel(const float* __restrict__ x,
                                                   float* __restrict__ xs) {
    const int g = blockIdx.x * 256 + threadIdx.x;   // g = n*64 + b
    const int n = g >> 6;
    const int b = g & 63;
    const float4* xp = reinterpret_cast<const float4*>(x + ((size_t)b * NCAP + n) * DIN);
    float4 a = xp[0], c4 = xp[1];
    float sq = a.x*a.x + a.y*a.y + a.z*a.z + a.w*a.w
             + c4.x*c4.x + c4.y*c4.y + c4.z*c4.z + c4.w*c4.w;
    float sc = sq / ((1.0f + sq) * sqrtf(sq));
    float4 o0 = {a.x*sc,  a.y*sc,  a.z*sc,  a.w*sc};
    float4 o1 = {c4.x*sc, c4.y*sc, c4.z*sc, c4.w*sc};
    float4* op = reinterpret_cast<float4*>(xs + (size_t)g * DIN);
    op[0] = o0;
    op[1] = o1;
}

// ---- sweep: one streaming pass over this block's n-range.
// PHASE 1: b=0 -> uniform coupling: S = sum_n u_n   (Z unused)
// PHASE 2: V = v1;       Z = sum exp(u.V), S = sum exp(u.V) u
// PHASE 3: V = v1+v2;    same accumulation, written to P3
template<int PHASE, int CH>
__global__ __launch_bounds__(SWEEP_BLK, 2) void sweep_kernel(const float* __restrict__ xs,
                                                             const float* __restrict__ W,
                                                             float* __restrict__ ws) {
    constexpr int NPC    = NCAP / CH;    // rows per block
    constexpr int NPW    = NPC / NW;     // rows per wave
    constexpr int NPAIRS = NPW / 2;      // row-pairs per wave
    using L = Layout<CH>;

    const int c  = blockIdx.x / CH;
    const int ch = blockIdx.x % CH;
    const int b  = threadIdx.x & 63;     // lane = batch
    const int w  = threadIdx.x >> 6;     // wave id

    // union: staging (8 waves x 4KB = 32KB) then reduction (8x17x64x4 = 34.8KB)
    __shared__ __align__(16) char smem[NW * (DOUT + 1) * NB * 4];

    float* P1 = ws + L::P1_OFF;
    float* P2 = ws + L::P2_OFF;
    float* P3 = ws + L::P3_OFF;

    // prologue: reconstruct V = sum of previous v's for (c, b)
    float V[DOUT];
    if (PHASE >= 2) {
        float sq = 0.f;
#pragma unroll
        for (int o = 0; o < DOUT; ++o) {
            float acc = 0.f;
#pragma unroll
            for (int k = 0; k < CH; ++k)
                acc += P1[(((size_t)c * CH + k) * DOUT + o) * NB + b];
            acc *= (1.0f / (float)NCAP);          // uniform c = 1/N
            V[o] = acc;
            sq += acc * acc;
        }
        const float sc = sq / ((1.0f + sq) * sqrtf(sq));
#pragma unroll
        for (int o = 0; o < DOUT; ++o) V[o] *= sc;   // V = v1
        if (PHASE == 3) {
            float Z2 = 0.f;
#pragma unroll
            for (int k = 0; k < CH; ++k)
                Z2 += P2[(((size_t)c * CH + k) * (DOUT + 1) + DOUT) * NB + b];
            const float rz = 1.0f / Z2;
            float s2[DOUT];
            float sq2 = 0.f;
#pragma unroll
            for (int o = 0; o < DOUT; ++o) {
                float acc = 0.f;
#pragma unroll
                for (int k = 0; k < CH; ++k)
                    acc += P2[(((size_t)c * CH + k) * (DOUT + 1) + o) * NB + b];
                acc *= rz;
                s2[o] = acc;
                sq2 += acc * acc;
            }
            const float sc2 = sq2 / ((1.0f + sq2) * sqrtf(sq2));
#pragma unroll
            for (int o = 0; o < DOUT; ++o) V[o] += s2[o] * sc2;  // V = v1+v2
        }
    }

    float S[DOUT];
#pragma unroll
    for (int o = 0; o < DOUT; ++o) S[o] = 0.f;
    float Z = 0.f;

    const int n0 = ch * NPC + w * NPW;
    const char* wsrc = (const char*)W + ((size_t)c * NCAP + n0) * ROW_BYTES;
    char* mybuf = smem + w * STG;

    // stage pair p (2 rows = 1KB): lane b loads 16B into mybuf[(p&3)*1024 + b*16]
    auto STAGE = [&](int p) {
        __builtin_amdgcn_global_load_lds(
            (const __attribute__((address_space(1))) void*)(wsrc + (size_t)p * 1024 + b * 16),
            (__attribute__((address_space(3))) void*)(mybuf + (p & 3) * 1024),
            16, 0, 0);
    };
    auto XROW = [&](int row, float4& xa, float4& xb) {
        const float4* xp = reinterpret_cast<const float4*>(
            xs + ((size_t)(n0 + row) * NB + b) * DIN);
        xa = xp[0];
        xb = xp[1];
    };
    auto ROW = [&](int p, int r, float4 xa, float4 xb) {
        const float4* wl = reinterpret_cast<const float4*>(mybuf + (p & 3) * 1024 + r * 512);
        const float xv[DIN] = {xa.x, xa.y, xa.z, xa.w, xb.x, xb.y, xb.z, xb.w};
        if (PHASE == 1) {
#pragma unroll
            for (int i = 0; i < DIN; ++i) {
                float4 q0 = wl[i*4+0], q1 = wl[i*4+1], q2 = wl[i*4+2], q3 = wl[i*4+3];
                const float xi = xv[i];
                S[ 0]=fmaf(xi,q0.x,S[ 0]); S[ 1]=fmaf(xi,q0.y,S[ 1]);
                S[ 2]=fmaf(xi,q0.z,S[ 2]); S[ 3]=fmaf(xi,q0.w,S[ 3]);
                S[ 4]=fmaf(xi,q1.x,S[ 4]); S[ 5]=fmaf(xi,q1.y,S[ 5]);
                S[ 6]=fmaf(xi,q1.z,S[ 6]); S[ 7]=fmaf(xi,q1.w,S[ 7]);
                S[ 8]=fmaf(xi,q2.x,S[ 8]); S[ 9]=fmaf(xi,q2.y,S[ 9]);
                S[10]=fmaf(xi,q2.z,S[10]); S[11]=fmaf(xi,q2.w,S[11]);
                S[12]=fmaf(xi,q3.x,S[12]); S[13]=fmaf(xi,q3.y,S[13]);
                S[14]=fmaf(xi,q3.z,S[14]); S[15]=fmaf(xi,q3.w,S[15]);
            }
        } else {
            float u[DOUT];
#pragma unroll
            for (int o = 0; o < DOUT; ++o) u[o] = 0.f;
#pragma unroll
            for (int i = 0; i < DIN; ++i) {
                float4 q0 = wl[i*4+0], q1 = wl[i*4+1], q2 = wl[i*4+2], q3 = wl[i*4+3];
                const float xi = xv[i];
                u[ 0]=fmaf(xi,q0.x,u[ 0]); u[ 1]=fmaf(xi,q0.y,u[ 1]);
                u[ 2]=fmaf(xi,q0.z,u[ 2]); u[ 3]=fmaf(xi,q0.w,u[ 3]);
                u[ 4]=fmaf(xi,q1.x,u[ 4]); u[ 5]=fmaf(xi,q1.y,u[ 5]);
                u[ 6]=fmaf(xi,q1.z,u[ 6]); u[ 7]=fmaf(xi,q1.w,u[ 7]);
                u[ 8]=fmaf(xi,q2.x,u[ 8]); u[ 9]=fmaf(xi,q2.y,u[ 9]);
                u[10]=fmaf(xi,q2.z,u[10]); u[11]=fmaf(xi,q2.w,u[11]);
                u[12]=fmaf(xi,q3.x,u[12]); u[13]=fmaf(xi,q3.y,u[13]);
                u[14]=fmaf(xi,q3.z,u[14]); u[15]=fmaf(xi,q3.w,u[15]);
            }
            float bd = 0.f;
#pragma unroll
            for (int o = 0; o < DOUT; ++o) bd = fmaf(u[o], V[o], bd);
            const float g = __expf(bd);   // |bd| <= ~48: fp32-safe, no max-sub
            Z += g;
#pragma unroll
            for (int o = 0; o < DOUT; ++o) S[o] = fmaf(g, u[o], S[o]);
        }
    };

    // ---- software pipeline: W staged 2 pairs ahead, xs 1 pair ahead.
    // FIFO per iter p: [STAGE(p+2)] [XROW(p+1) x4]. Steady-state wait = vmcnt(5).
    STAGE(0); SB();
    STAGE(1); SB();
    float4 ca0, ca1, cb0, cb1, na0, na1, nb0, nb1;
    XROW(0, ca0, ca1);
    XROW(1, cb0, cb1);
    SB();

#pragma unroll 1
    for (int p = 0; p < NPAIRS; ++p) {
        if (p + 2 < NPAIRS) STAGE(p + 2);
        SB();
        if (p + 1 < NPAIRS) {
            XROW(2 * (p + 1),     na0, na1);
            XROW(2 * (p + 1) + 1, nb0, nb1);
        }
        SB();
        if (p < NPAIRS - 2)       { WAITV(5); }
        else if (p == NPAIRS - 2) { WAITV(4); }
        else                      { WAITV(0); }
        SB();
        ROW(p, 0, ca0, ca1);
        ROW(p, 1, cb0, cb1);
        ca0 = na0; ca1 = na1; cb0 = nb0; cb1 = nb1;
    }

    // ---- cross-wave merge (reuse smem after all waves finish staging reads)
    __syncthreads();
    float (*red)[DOUT + 1][NB] = reinterpret_cast<float (*)[DOUT + 1][NB]>(smem);
#pragma unroll
    for (int o = 0; o < DOUT; ++o) red[w][o][b] = S[o];
    red[w][DOUT][b] = Z;
    __syncthreads();
    for (int idx = threadIdx.x; idx < (DOUT + 1) * NB; idx += SWEEP_BLK) {
        const int slot = idx >> 6;
        const int bb   = idx & 63;
        float acc = 0.f;
#pragma unroll
        for (int k = 0; k < NW; ++k) acc += red[k][slot][bb];
        if (PHASE == 1) {
            if (slot < DOUT)
                P1[(((size_t)c * CH + ch) * DOUT + slot) * NB + bb] = acc;
        } else {
            float* P = (PHASE == 2) ? P2 : P3;
            P[(((size_t)c * CH + ch) * (DOUT + 1) + slot) * NB + bb] = acc;
        }
    }
}

// ---- final: merge P3 -> v3, leaky^2, per-batch normalize, write out[b,c,o]
template<int CH>
__global__ __launch_bounds__(256) void final_kernel(const float* __restrict__ ws_ro,
                                                    float* __restrict__ out) {
    using L = Layout<CH>;
    const float* P3 = ws_ro + L::P3_OFF;
    const int b    = blockIdx.x;
    const int tid  = threadIdx.x;
    const int c    = tid >> 1;
    const int half = tid & 1;   // 8 of 16 Dout elements each

    float Zt = 0.f;
#pragma unroll
    for (int k = 0; k < CH; ++k)
        Zt += P3[(((size_t)c * CH + k) * (DOUT + 1) + DOUT) * NB + b];
    const float rz = 1.0f / Zt;

    float s[8];
    float sqh = 0.f;
#pragma unroll
    for (int j = 0; j < 8; ++j) {
        const int o = half * 8 + j;
        float acc = 0.f;
#pragma unroll
        for (int k = 0; k < CH; ++k)
            acc += P3[(((size_t)c * CH + k) * (DOUT + 1) + o) * NB + b];
        acc *= rz;
        s[j] = acc;
        sqh += acc * acc;
    }
    const float sq = sqh + __shfl_xor(sqh, 1);
    const float sc = sq / ((1.0f + sq) * sqrtf(sq));

    float val[8];
    float ps = 0.f;
#pragma unroll
    for (int j = 0; j < 8; ++j) {
        const float v = s[j] * sc;
        const float l = v > 0.f ? v : 0.01f * v;
        val[j] = l * l;
        ps += val[j];
    }
#pragma unroll
    for (int off = 1; off < 64; off <<= 1) ps += __shfl_xor(ps, off);
    __shared__ float wsum[4];
    if ((tid & 63) == 0) wsum[tid >> 6] = ps;
    __syncthreads();
    const float inv = 1.0f / (wsum[0] + wsum[1] + wsum[2] + wsum[3]);
#pragma unroll
    for (int j = 0; j < 8; ++j)
        out[((size_t)b * NCLS + c) * DOUT + half * 8 + j] = val[j] * inv;
}

extern "C" void kernel_launch(void* const* d_in, const int* in_sizes, int n_in,
                              void* d_out, int out_size, void* d_ws, size_t ws_size,
                              hipStream_t stream) {
    const float* x = (const float*)d_in[0];
    const float* W = (const float*)d_in[1];
    float* out = (float*)d_out;
    float* ws  = (float*)d_ws;

    hipLaunchKernelGGL(prep_kernel, dim3(NCAP * NB / 256), dim3(256), 0, stream,
                       x, ws);

    if (ws_size >= Layout<8>::TOTAL * sizeof(float)) {
        hipLaunchKernelGGL((sweep_kernel<1, 8>), dim3(NCLS * 8), dim3(SWEEP_BLK), 0, stream,
                           ws, W, ws);
        hipLaunchKernelGGL((sweep_kernel<2, 8>), dim3(NCLS * 8), dim3(SWEEP_BLK), 0, stream,
                           ws, W, ws);
        hipLaunchKernelGGL((sweep_kernel<3, 8>), dim3(NCLS * 8), dim3(SWEEP_BLK), 0, stream,
                           ws, W, ws);
        hipLaunchKernelGGL((final_kernel<8>), dim3(NB), dim3(256), 0, stream, ws, out);
    } else {
        hipLaunchKernelGGL((sweep_kernel<1, 4>), dim3(NCLS * 4), dim3(SWEEP_BLK), 0, stream,
                           ws, W, ws);
        hipLaunchKernelGGL((sweep_kernel<2, 4>), dim3(NCLS * 4), dim3(SWEEP_BLK), 0, stream,
                           ws, W, ws);
        hipLaunchKernelGGL((sweep_kernel<3, 4>), dim3(NCLS * 4), dim3(SWEEP_BLK), 0, stream,
                           ws, W, ws);
        hipLaunchKernelGGL((final_kernel<4>), dim3(NB), dim3(256), 0, stream, ws, out);
    }
}

// Round 9
// 177.131 us; speedup vs baseline: 2.8042x; 1.1232x over previous
//
#include <hip/hip_runtime.h>
#include <math.h>

// CapsNet dynamic routing, fp32 — streaming sweeps, V hoisted out of sweeps.
//
// R8 post-mortem: CH=8's in-sweep V-reconstruction prologue inflated VGPR
// 60->80 -> 3 blocks/CU -> 1.33 grid rounds -> sweeps 85us. R9: hoist the
// V merge+squash into tiny vupd kernels writing V[c][o][b] to ws; sweeps
// 2/3 just load 16 floats. Hot loop is byte-identical to R5's proven
// 60-VGPR body; CH=8 grid (1024 blocks) -> 4 blocks/CU, one full round.
//
// x: [B=64, N=1152, Din=8], W: [C=128, N=1152, Din=8, Dout=16]
// out: [B=64, C=128, Dout=16]

constexpr int NCAP = 1152;
constexpr int DIN  = 8;
constexpr int DOUT = 16;
constexpr int NCLS = 128;
constexpr int NB   = 64;

constexpr int NW        = 8;                  // waves per sweep block
constexpr int SWEEP_BLK = NW * 64;            // 512 threads
constexpr int STG       = 4096;               // per-wave staging: 4 bufs x 1KB
constexpr int ROW_BYTES = DIN * DOUT * 4;     // 512 B per W row

template<int CH> struct Layout {
    static constexpr size_t XS_OFF = 0;
    static constexpr size_t XS_SZ  = (size_t)NCAP * NB * DIN;          // 589,824
    static constexpr size_t P1_OFF = XS_OFF + XS_SZ;
    static constexpr size_t P1_SZ  = (size_t)NCLS * CH * DOUT * NB;
    static constexpr size_t P2_OFF = P1_OFF + P1_SZ;
    static constexpr size_t P23_SZ = (size_t)NCLS * CH * (DOUT + 1) * NB;
    static constexpr size_t P3_OFF = P2_OFF + P23_SZ;
    static constexpr size_t VA_OFF = P3_OFF + P23_SZ;
    static constexpr size_t V_SZ   = (size_t)NCLS * DOUT * NB;         // 131,072
    static constexpr size_t VB_OFF = VA_OFF + V_SZ;
    static constexpr size_t TOTAL  = VB_OFF + V_SZ;   // floats
};

#define WAITV(N) asm volatile("s_waitcnt vmcnt(" #N ")" ::: "memory")
#define SB() __builtin_amdgcn_sched_barrier(0)

// ---- prep: squash(x) and transpose to xs[n][b][0..7]
__global__ __launch_bounds__(256) void prep_kernel(const float* __restrict__ x,
                                                   float* __restrict__ xs) {
    const int g = blockIdx.x * 256 + threadIdx.x;   // g = n*64 + b
    const int n = g >> 6;
    const int b = g & 63;
    const float4* xp = reinterpret_cast<const float4*>(x + ((size_t)b * NCAP + n) * DIN);
    float4 a = xp[0], c4 = xp[1];
    float sq = a.x*a.x + a.y*a.y + a.z*a.z + a.w*a.w
             + c4.x*c4.x + c4.y*c4.y + c4.z*c4.z + c4.w*c4.w;
    float sc = sq / ((1.0f + sq) * sqrtf(sq));
    float4 o0 = {a.x*sc,  a.y*sc,  a.z*sc,  a.w*sc};
    float4 o1 = {c4.x*sc, c4.y*sc, c4.z*sc, c4.w*sc};
    float4* op = reinterpret_cast<float4*>(xs + (size_t)g * DIN);
    op[0] = o0;
    op[1] = o1;
}

// ---- sweep: one streaming pass over this block's n-range.
// WEIGHTED=false: S = sum_n u_n (P gets 16 slots)
// WEIGHTED=true : reads V[c][o][b]; Z = sum exp(u.V), S = sum exp(u.V) u (17 slots)
template<bool WEIGHTED, int CH>
__global__ __launch_bounds__(SWEEP_BLK, 2) void sweep_kernel(const float* __restrict__ xs,
                                                             const float* __restrict__ W,
                                                             float* __restrict__ P,
                                                             const float* __restrict__ vbuf) {
    constexpr int NPC    = NCAP / CH;    // rows per block
    constexpr int NPW    = NPC / NW;     // rows per wave
    constexpr int NPAIRS = NPW / 2;      // row-pairs per wave

    const int bg = blockIdx.x;           // = c*CH + ch
    const int c  = bg / CH;
    const int ch = bg % CH;
    const int b  = threadIdx.x & 63;     // lane = batch
    const int w  = threadIdx.x >> 6;     // wave id

    // union: staging (8 waves x 4KB = 32KB) then reduction (8x17x64x4 = 34.8KB)
    __shared__ __align__(16) char smem[NW * (DOUT + 1) * NB * 4];

    // prologue: 16 coalesced loads of V (weighted only)
    float V[DOUT];
    if (WEIGHTED) {
        const float* vb = vbuf + (size_t)c * DOUT * NB + b;
#pragma unroll
        for (int o = 0; o < DOUT; ++o) V[o] = vb[o * NB];
    }

    float S[DOUT];
#pragma unroll
    for (int o = 0; o < DOUT; ++o) S[o] = 0.f;
    float Z = 0.f;

    const int n0 = ch * NPC + w * NPW;
    const char* wsrc = (const char*)W + ((size_t)c * NCAP + n0) * ROW_BYTES;
    char* mybuf = smem + w * STG;

    // stage pair p (2 rows = 1KB): lane b loads 16B into mybuf[(p&3)*1024 + b*16]
    auto STAGE = [&](int p) {
        __builtin_amdgcn_global_load_lds(
            (const __attribute__((address_space(1))) void*)(wsrc + (size_t)p * 1024 + b * 16),
            (__attribute__((address_space(3))) void*)(mybuf + (p & 3) * 1024),
            16, 0, 0);
    };
    auto XROW = [&](int row, float4& xa, float4& xb) {
        const float4* xp = reinterpret_cast<const float4*>(
            xs + ((size_t)(n0 + row) * NB + b) * DIN);
        xa = xp[0];
        xb = xp[1];
    };
    auto ROW = [&](int p, int r, float4 xa, float4 xb) {
        const float4* wl = reinterpret_cast<const float4*>(mybuf + (p & 3) * 1024 + r * 512);
        const float xv[DIN] = {xa.x, xa.y, xa.z, xa.w, xb.x, xb.y, xb.z, xb.w};
        if (!WEIGHTED) {
#pragma unroll
            for (int i = 0; i < DIN; ++i) {
                float4 q0 = wl[i*4+0], q1 = wl[i*4+1], q2 = wl[i*4+2], q3 = wl[i*4+3];
                const float xi = xv[i];
                S[ 0]=fmaf(xi,q0.x,S[ 0]); S[ 1]=fmaf(xi,q0.y,S[ 1]);
                S[ 2]=fmaf(xi,q0.z,S[ 2]); S[ 3]=fmaf(xi,q0.w,S[ 3]);
                S[ 4]=fmaf(xi,q1.x,S[ 4]); S[ 5]=fmaf(xi,q1.y,S[ 5]);
                S[ 6]=fmaf(xi,q1.z,S[ 6]); S[ 7]=fmaf(xi,q1.w,S[ 7]);
                S[ 8]=fmaf(xi,q2.x,S[ 8]); S[ 9]=fmaf(xi,q2.y,S[ 9]);
                S[10]=fmaf(xi,q2.z,S[10]); S[11]=fmaf(xi,q2.w,S[11]);
                S[12]=fmaf(xi,q3.x,S[12]); S[13]=fmaf(xi,q3.y,S[13]);
                S[14]=fmaf(xi,q3.z,S[14]); S[15]=fmaf(xi,q3.w,S[15]);
            }
        } else {
            float u[DOUT];
#pragma unroll
            for (int o = 0; o < DOUT; ++o) u[o] = 0.f;
#pragma unroll
            for (int i = 0; i < DIN; ++i) {
                float4 q0 = wl[i*4+0], q1 = wl[i*4+1], q2 = wl[i*4+2], q3 = wl[i*4+3];
                const float xi = xv[i];
                u[ 0]=fmaf(xi,q0.x,u[ 0]); u[ 1]=fmaf(xi,q0.y,u[ 1]);
                u[ 2]=fmaf(xi,q0.z,u[ 2]); u[ 3]=fmaf(xi,q0.w,u[ 3]);
                u[ 4]=fmaf(xi,q1.x,u[ 4]); u[ 5]=fmaf(xi,q1.y,u[ 5]);
                u[ 6]=fmaf(xi,q1.z,u[ 6]); u[ 7]=fmaf(xi,q1.w,u[ 7]);
                u[ 8]=fmaf(xi,q2.x,u[ 8]); u[ 9]=fmaf(xi,q2.y,u[ 9]);
                u[10]=fmaf(xi,q2.z,u[10]); u[11]=fmaf(xi,q2.w,u[11]);
                u[12]=fmaf(xi,q3.x,u[12]); u[13]=fmaf(xi,q3.y,u[13]);
                u[14]=fmaf(xi,q3.z,u[14]); u[15]=fmaf(xi,q3.w,u[15]);
            }
            float bd = 0.f;
#pragma unroll
            for (int o = 0; o < DOUT; ++o) bd = fmaf(u[o], V[o], bd);
            const float g = __expf(bd);   // |bd| <= ~48: fp32-safe, no max-sub
            Z += g;
#pragma unroll
            for (int o = 0; o < DOUT; ++o) S[o] = fmaf(g, u[o], S[o]);
        }
    };

    // ---- software pipeline: W staged 2 pairs ahead, xs 1 pair ahead.
    // FIFO per iter p: [STAGE(p+2)] [XROW(p+1) x4]. Steady-state wait = vmcnt(5).
    STAGE(0); SB();
    STAGE(1); SB();
    float4 ca0, ca1, cb0, cb1, na0, na1, nb0, nb1;
    XROW(0, ca0, ca1);
    XROW(1, cb0, cb1);
    SB();

#pragma unroll 1
    for (int p = 0; p < NPAIRS; ++p) {
        if (p + 2 < NPAIRS) STAGE(p + 2);
        SB();
        if (p + 1 < NPAIRS) {
            XROW(2 * (p + 1),     na0, na1);
            XROW(2 * (p + 1) + 1, nb0, nb1);
        }
        SB();
        if (p < NPAIRS - 2)       { WAITV(5); }
        else if (p == NPAIRS - 2) { WAITV(4); }
        else                      { WAITV(0); }
        SB();
        ROW(p, 0, ca0, ca1);
        ROW(p, 1, cb0, cb1);
        ca0 = na0; ca1 = na1; cb0 = nb0; cb1 = nb1;
    }

    // ---- cross-wave merge (reuse smem after all waves finish staging reads)
    __syncthreads();
    float (*red)[DOUT + 1][NB] = reinterpret_cast<float (*)[DOUT + 1][NB]>(smem);
#pragma unroll
    for (int o = 0; o < DOUT; ++o) red[w][o][b] = S[o];
    red[w][DOUT][b] = Z;
    __syncthreads();
    for (int idx = threadIdx.x; idx < (DOUT + 1) * NB; idx += SWEEP_BLK) {
        const int slot = idx >> 6;
        const int bb   = idx & 63;
        float acc = 0.f;
#pragma unroll
        for (int k = 0; k < NW; ++k) acc += red[k][slot][bb];
        if (!WEIGHTED) {
            if (slot < DOUT)
                P[((size_t)bg * DOUT + slot) * NB + bb] = acc;
        } else {
            P[((size_t)bg * (DOUT + 1) + slot) * NB + bb] = acc;
        }
    }
}

// ---- vupd: merge partials -> V for the next sweep.
// MODE 1: V = squash(sum(P1)/N)                     -> vout
// MODE 2: V = vin + squash(sum(P2 S)/sum(P2 Z))     -> vout
template<int MODE, int CH>
__global__ __launch_bounds__(64) void vupd_kernel(const float* __restrict__ P,
                                                  const float* __restrict__ vin,
                                                  float* __restrict__ vout) {
    const int c = blockIdx.x;
    const int b = threadIdx.x;   // lane = batch

    float s[DOUT];
    float sq = 0.f;
    if (MODE == 1) {
#pragma unroll
        for (int o = 0; o < DOUT; ++o) {
            float acc = 0.f;
#pragma unroll
            for (int k = 0; k < CH; ++k)
                acc += P[(((size_t)c * CH + k) * DOUT + o) * NB + b];
            acc *= (1.0f / (float)NCAP);
            s[o] = acc;
            sq += acc * acc;
        }
    } else {
        float Zt = 0.f;
#pragma unroll
        for (int k = 0; k < CH; ++k)
            Zt += P[(((size_t)c * CH + k) * (DOUT + 1) + DOUT) * NB + b];
        const float rz = 1.0f / Zt;
#pragma unroll
        for (int o = 0; o < DOUT; ++o) {
            float acc = 0.f;
#pragma unroll
            for (int k = 0; k < CH; ++k)
                acc += P[(((size_t)c * CH + k) * (DOUT + 1) + o) * NB + b];
            acc *= rz;
            s[o] = acc;
            sq += acc * acc;
        }
    }
    const float sc = sq / ((1.0f + sq) * sqrtf(sq));
#pragma unroll
    for (int o = 0; o < DOUT; ++o) {
        float v = s[o] * sc;
        if (MODE == 2) v += vin[((size_t)c * DOUT + o) * NB + b];
        vout[((size_t)c * DOUT + o) * NB + b] = v;
    }
}

// ---- final: merge P3 -> v3, leaky^2, per-batch normalize, write out[b,c,o]
template<int CH>
__global__ __launch_bounds__(256) void final_kernel(const float* __restrict__ P3,
                                                    float* __restrict__ out) {
    const int b    = blockIdx.x;
    const int tid  = threadIdx.x;
    const int c    = tid >> 1;
    const int half = tid & 1;   // 8 of 16 Dout elements each

    float Zt = 0.f;
#pragma unroll
    for (int k = 0; k < CH; ++k)
        Zt += P3[(((size_t)c * CH + k) * (DOUT + 1) + DOUT) * NB + b];
    const float rz = 1.0f / Zt;

    float s[8];
    float sqh = 0.f;
#pragma unroll
    for (int j = 0; j < 8; ++j) {
        const int o = half * 8 + j;
        float acc = 0.f;
#pragma unroll
        for (int k = 0; k < CH; ++k)
            acc += P3[(((size_t)c * CH + k) * (DOUT + 1) + o) * NB + b];
        acc *= rz;
        s[j] = acc;
        sqh += acc * acc;
    }
    const float sq = sqh + __shfl_xor(sqh, 1);
    const float sc = sq / ((1.0f + sq) * sqrtf(sq));

    float val[8];
    float ps = 0.f;
#pragma unroll
    for (int j = 0; j < 8; ++j) {
        const float v = s[j] * sc;
        const float l = v > 0.f ? v : 0.01f * v;
        val[j] = l * l;
        ps += val[j];
    }
#pragma unroll
    for (int off = 1; off < 64; off <<= 1) ps += __shfl_xor(ps, off);
    __shared__ float wsum[4];
    if ((tid & 63) == 0) wsum[tid >> 6] = ps;
    __syncthreads();
    const float inv = 1.0f / (wsum[0] + wsum[1] + wsum[2] + wsum[3]);
#pragma unroll
    for (int j = 0; j < 8; ++j)
        out[((size_t)b * NCLS + c) * DOUT + half * 8 + j] = val[j] * inv;
}

template<int CH>
static void run(const float* x, const float* W, float* out, float* ws,
                hipStream_t stream) {
    using L = Layout<CH>;
    float* xs = ws + L::XS_OFF;
    float* P1 = ws + L::P1_OFF;
    float* P2 = ws + L::P2_OFF;
    float* P3 = ws + L::P3_OFF;
    float* VA = ws + L::VA_OFF;
    float* VB = ws + L::VB_OFF;

    hipLaunchKernelGGL(prep_kernel, dim3(NCAP * NB / 256), dim3(256), 0, stream, x, xs);
    hipLaunchKernelGGL((sweep_kernel<false, CH>), dim3(NCLS * CH), dim3(SWEEP_BLK), 0,
                       stream, xs, W, P1, nullptr);
    hipLaunchKernelGGL((vupd_kernel<1, CH>), dim3(NCLS), dim3(64), 0, stream,
                       P1, nullptr, VA);
    hipLaunchKernelGGL((sweep_kernel<true, CH>), dim3(NCLS * CH), dim3(SWEEP_BLK), 0,
                       stream, xs, W, P2, VA);
    hipLaunchKernelGGL((vupd_kernel<2, CH>), dim3(NCLS), dim3(64), 0, stream,
                       P2, VA, VB);
    hipLaunchKernelGGL((sweep_kernel<true, CH>), dim3(NCLS * CH), dim3(SWEEP_BLK), 0,
                       stream, xs, W, P3, VB);
    hipLaunchKernelGGL((final_kernel<CH>), dim3(NB), dim3(256), 0, stream, P3, out);
}

extern "C" void kernel_launch(void* const* d_in, const int* in_sizes, int n_in,
                              void* d_out, int out_size, void* d_ws, size_t ws_size,
                              hipStream_t stream) {
    const float* x = (const float*)d_in[0];
    const float* W = (const float*)d_in[1];
    float* out = (float*)d_out;
    float* ws  = (float*)d_ws;

    if (ws_size >= Layout<8>::TOTAL * sizeof(float)) {
        run<8>(x, W, out, ws, stream);
    } else {
        run<4>(x, W, out, ws, stream);
    }
}

// Round 10
// 144.774 us; speedup vs baseline: 3.4309x; 1.2235x over previous
//
#include <hip/hip_runtime.h>
#include <math.h>

// CapsNet dynamic routing — fp16-W streaming sweeps with v_dot2_f32_f16.
//
// R9 diagnosis: sweeps are LDS-read-port-bound (R5@16waves/CU == R9@32waves/CU
// == 57us; 576 rows/CU x 32 ds_read_b128 x ~8cyc ~= 61us). R10: halve the LDS
// stream — W converted once to fp16 half2-pairs (256B/row), u computed with
// v_dot2_f32_f16 (fp32 accum): 16 b128/row instead of 32, 64 dot2 instead of
// 128 FMA. x pre-squashed+converted to fp16 (1 b128/row/lane). All routing
// math (V, exp, squash, softmax) stays fp32. ws 44.5MB guarded; R9 fp32 path
// kept as fallback.
//
// x: [B=64, N=1152, Din=8], W: [C=128, N=1152, Din=8, Dout=16]
// out: [B=64, C=128, Dout=16]

typedef _Float16 half_t;
typedef _Float16 half2_t __attribute__((ext_vector_type(2)));

constexpr int NCAP = 1152;
constexpr int DIN  = 8;
constexpr int DOUT = 16;
constexpr int NCLS = 128;
constexpr int NB   = 64;

constexpr int NW        = 8;                  // waves per sweep block
constexpr int SWEEP_BLK = NW * 64;            // 512 threads
constexpr int STG       = 4096;               // per-wave staging: 4 bufs x 1KB

// ---------- fp16 path layout (float units) ----------
struct L16 {
    static constexpr int    CH     = 4;                              // 512 blocks
    static constexpr size_t XSH_OFF = 0;                             // x fp16: [n][b] 16B
    static constexpr size_t XSH_SZ  = (size_t)NCAP * NB * 4;         // 294,912
    static constexpr size_t WH_OFF  = XSH_OFF + XSH_SZ;              // W fp16: 256B/row
    static constexpr size_t WH_SZ   = (size_t)NCLS * NCAP * 64;      // 9,437,184
    static constexpr size_t P1_OFF  = WH_OFF + WH_SZ;
    static constexpr size_t P1_SZ   = (size_t)NCLS * CH * DOUT * NB;
    static constexpr size_t P2_OFF  = P1_OFF + P1_SZ;
    static constexpr size_t P23_SZ  = (size_t)NCLS * CH * (DOUT + 1) * NB;
    static constexpr size_t P3_OFF  = P2_OFF + P23_SZ;
    static constexpr size_t VA_OFF  = P3_OFF + P23_SZ;
    static constexpr size_t V_SZ    = (size_t)NCLS * DOUT * NB;
    static constexpr size_t VB_OFF  = VA_OFF + V_SZ;
    static constexpr size_t TOTAL   = VB_OFF + V_SZ;                 // ~11.6M floats
};

// ---------- fp32 fallback layout (R9) ----------
template<int CH> struct Layout {
    static constexpr size_t XS_OFF = 0;
    static constexpr size_t XS_SZ  = (size_t)NCAP * NB * DIN;
    static constexpr size_t P1_OFF = XS_OFF + XS_SZ;
    static constexpr size_t P1_SZ  = (size_t)NCLS * CH * DOUT * NB;
    static constexpr size_t P2_OFF = P1_OFF + P1_SZ;
    static constexpr size_t P23_SZ = (size_t)NCLS * CH * (DOUT + 1) * NB;
    static constexpr size_t P3_OFF = P2_OFF + P23_SZ;
    static constexpr size_t VA_OFF = P3_OFF + P23_SZ;
    static constexpr size_t V_SZ   = (size_t)NCLS * DOUT * NB;
    static constexpr size_t VB_OFF = VA_OFF + V_SZ;
    static constexpr size_t TOTAL  = VB_OFF + V_SZ;
};

#define WAITV(N) asm volatile("s_waitcnt vmcnt(" #N ")" ::: "memory")
#define SB() __builtin_amdgcn_sched_barrier(0)

__device__ __forceinline__ float fdot2(half2_t a, half2_t b, float c) {
#if __has_builtin(__builtin_amdgcn_fdot2)
    return __builtin_amdgcn_fdot2(a, b, c, false);
#else
    asm volatile("v_dot2_f32_f16 %0, %1, %2, %0" : "+v"(c) : "v"(a), "v"(b));
    return c;
#endif
}
__device__ __forceinline__ half2_t bch2(float f) { return __builtin_bit_cast(half2_t, f); }
__device__ __forceinline__ float bcf(half2_t h) { return __builtin_bit_cast(float, h); }

// ---- prep_x: squash(x), convert fp16, transpose to xsh[n][b] (4 half2 = 16B)
__global__ __launch_bounds__(256) void prep_x(const float* __restrict__ x,
                                              float* __restrict__ xsh) {
    const int g = blockIdx.x * 256 + threadIdx.x;   // g = n*64 + b
    const int n = g >> 6;
    const int b = g & 63;
    const float4* xp = reinterpret_cast<const float4*>(x + ((size_t)b * NCAP + n) * DIN);
    float4 a = xp[0], c4 = xp[1];
    float sq = a.x*a.x + a.y*a.y + a.z*a.z + a.w*a.w
             + c4.x*c4.x + c4.y*c4.y + c4.z*c4.z + c4.w*c4.w;
    float sc = sq / ((1.0f + sq) * sqrtf(sq));
    half2_t h0 = {(half_t)(a.x*sc),  (half_t)(a.y*sc)};
    half2_t h1 = {(half_t)(a.z*sc),  (half_t)(a.w*sc)};
    half2_t h2 = {(half_t)(c4.x*sc), (half_t)(c4.y*sc)};
    half2_t h3 = {(half_t)(c4.z*sc), (half_t)(c4.w*sc)};
    float4 o;
    o.x = bcf(h0); o.y = bcf(h1); o.z = bcf(h2); o.w = bcf(h3);
    reinterpret_cast<float4*>(xsh)[g] = o;
}

// ---- prep_w: W row (c,n) -> fp16 half2 pairs, layout [ip][o], 256B/row.
// thread = (row, ip): reads W[row][2ip..2ip+1][0..15] (128B), writes 64B.
__global__ __launch_bounds__(256) void prep_w(const float* __restrict__ W,
                                              float* __restrict__ wh) {
    const int g   = blockIdx.x * 256 + threadIdx.x;
    const int row = g >> 2;
    const int ip  = g & 3;
    const float4* src = reinterpret_cast<const float4*>(W + (size_t)row * 128 + ip * 32);
    float4 a0 = src[0], a1 = src[1], a2 = src[2], a3 = src[3];   // W[2ip][0..15]
    float4 b0 = src[4], b1 = src[5], b2 = src[6], b3 = src[7];   // W[2ip+1][0..15]
    const float f0[16] = {a0.x,a0.y,a0.z,a0.w, a1.x,a1.y,a1.z,a1.w,
                          a2.x,a2.y,a2.z,a2.w, a3.x,a3.y,a3.z,a3.w};
    const float f1[16] = {b0.x,b0.y,b0.z,b0.w, b1.x,b1.y,b1.z,b1.w,
                          b2.x,b2.y,b2.z,b2.w, b3.x,b3.y,b3.z,b3.w};
    float4 d[4];
#pragma unroll
    for (int j = 0; j < 4; ++j) {
        half2_t h0 = {(half_t)f0[4*j+0], (half_t)f1[4*j+0]};
        half2_t h1 = {(half_t)f0[4*j+1], (half_t)f1[4*j+1]};
        half2_t h2 = {(half_t)f0[4*j+2], (half_t)f1[4*j+2]};
        half2_t h3 = {(half_t)f0[4*j+3], (half_t)f1[4*j+3]};
        d[j].x = bcf(h0); d[j].y = bcf(h1); d[j].z = bcf(h2); d[j].w = bcf(h3);
    }
    float4* dst = reinterpret_cast<float4*>(wh + (size_t)row * 64 + ip * 16);
    dst[0] = d[0]; dst[1] = d[1]; dst[2] = d[2]; dst[3] = d[3];
}

// ---- fp16 sweep: quads of 4 rows (1KB) staged via global_load_lds.
template<bool WEIGHTED>
__global__ __launch_bounds__(SWEEP_BLK, 2) void sweep_h(const float* __restrict__ xsh,
                                                        const float* __restrict__ wh,
                                                        float* __restrict__ P,
                                                        const float* __restrict__ vbuf) {
    constexpr int CH   = L16::CH;
    constexpr int NPC  = NCAP / CH;      // 288 rows per block
    constexpr int NPW  = NPC / NW;       // 36 rows per wave
    constexpr int NPQ  = NPW / 4;        // 9 quads per wave

    const int bg = blockIdx.x;           // = c*CH + ch
    const int c  = bg / CH;
    const int ch = bg % CH;
    const int b  = threadIdx.x & 63;
    const int w  = threadIdx.x >> 6;

    __shared__ __align__(16) char smem[NW * (DOUT + 1) * NB * 4];

    float V[DOUT];
    if (WEIGHTED) {
        const float* vb = vbuf + (size_t)c * DOUT * NB + b;
#pragma unroll
        for (int o = 0; o < DOUT; ++o) V[o] = vb[o * NB];
    }

    float S[DOUT];
#pragma unroll
    for (int o = 0; o < DOUT; ++o) S[o] = 0.f;
    float Z = 0.f;

    const int n0 = ch * NPC + w * NPW;
    const char* wsrc = (const char*)wh + ((size_t)c * NCAP + n0) * 256;
    char* mybuf = smem + w * STG;

    auto STAGE = [&](int q) {   // stage quad q: 4 rows = 1KB, lane b -> b*16
        __builtin_amdgcn_global_load_lds(
            (const __attribute__((address_space(1))) void*)(wsrc + (size_t)q * 1024 + b * 16),
            (__attribute__((address_space(3))) void*)(mybuf + (q & 3) * 1024),
            16, 0, 0);
    };
    auto XROW = [&](int row, float4& xr) {
        xr = reinterpret_cast<const float4*>(xsh)[(size_t)(n0 + row) * NB + b];
    };
    auto ROW = [&](int q, int r, float4 xr) {
        const float4* wl = reinterpret_cast<const float4*>(mybuf + (q & 3) * 1024 + r * 256);
        half2_t xp0 = bch2(xr.x), xp1 = bch2(xr.y), xp2 = bch2(xr.z), xp3 = bch2(xr.w);
        if (!WEIGHTED) {
#pragma unroll
            for (int ip = 0; ip < 4; ++ip) {
                const half2_t xp = (ip == 0) ? xp0 : (ip == 1) ? xp1 : (ip == 2) ? xp2 : xp3;
                float4 w0 = wl[ip*4+0], w1 = wl[ip*4+1], w2 = wl[ip*4+2], w3 = wl[ip*4+3];
                S[ 0]=fdot2(xp,bch2(w0.x),S[ 0]); S[ 1]=fdot2(xp,bch2(w0.y),S[ 1]);
                S[ 2]=fdot2(xp,bch2(w0.z),S[ 2]); S[ 3]=fdot2(xp,bch2(w0.w),S[ 3]);
                S[ 4]=fdot2(xp,bch2(w1.x),S[ 4]); S[ 5]=fdot2(xp,bch2(w1.y),S[ 5]);
                S[ 6]=fdot2(xp,bch2(w1.z),S[ 6]); S[ 7]=fdot2(xp,bch2(w1.w),S[ 7]);
                S[ 8]=fdot2(xp,bch2(w2.x),S[ 8]); S[ 9]=fdot2(xp,bch2(w2.y),S[ 9]);
                S[10]=fdot2(xp,bch2(w2.z),S[10]); S[11]=fdot2(xp,bch2(w2.w),S[11]);
                S[12]=fdot2(xp,bch2(w3.x),S[12]); S[13]=fdot2(xp,bch2(w3.y),S[13]);
                S[14]=fdot2(xp,bch2(w3.z),S[14]); S[15]=fdot2(xp,bch2(w3.w),S[15]);
            }
        } else {
            float u[DOUT];
#pragma unroll
            for (int o = 0; o < DOUT; ++o) u[o] = 0.f;
#pragma unroll
            for (int ip = 0; ip < 4; ++ip) {
                const half2_t xp = (ip == 0) ? xp0 : (ip == 1) ? xp1 : (ip == 2) ? xp2 : xp3;
                float4 w0 = wl[ip*4+0], w1 = wl[ip*4+1], w2 = wl[ip*4+2], w3 = wl[ip*4+3];
                u[ 0]=fdot2(xp,bch2(w0.x),u[ 0]); u[ 1]=fdot2(xp,bch2(w0.y),u[ 1]);
                u[ 2]=fdot2(xp,bch2(w0.z),u[ 2]); u[ 3]=fdot2(xp,bch2(w0.w),u[ 3]);
                u[ 4]=fdot2(xp,bch2(w1.x),u[ 4]); u[ 5]=fdot2(xp,bch2(w1.y),u[ 5]);
                u[ 6]=fdot2(xp,bch2(w1.z),u[ 6]); u[ 7]=fdot2(xp,bch2(w1.w),u[ 7]);
                u[ 8]=fdot2(xp,bch2(w2.x),u[ 8]); u[ 9]=fdot2(xp,bch2(w2.y),u[ 9]);
                u[10]=fdot2(xp,bch2(w2.z),u[10]); u[11]=fdot2(xp,bch2(w2.w),u[11]);
                u[12]=fdot2(xp,bch2(w3.x),u[12]); u[13]=fdot2(xp,bch2(w3.y),u[13]);
                u[14]=fdot2(xp,bch2(w3.z),u[14]); u[15]=fdot2(xp,bch2(w3.w),u[15]);
            }
            float bd = 0.f;
#pragma unroll
            for (int o = 0; o < DOUT; ++o) bd = fmaf(u[o], V[o], bd);
            const float g = __expf(bd);
            Z += g;
#pragma unroll
            for (int o = 0; o < DOUT; ++o) S[o] = fmaf(g, u[o], S[o]);
        }
    };

    // pipeline: W quads staged 2 ahead, x 1 quad ahead. Steady wait = vmcnt(5).
    STAGE(0); SB();
    STAGE(1); SB();
    float4 cx0, cx1, cx2, cx3, nx0, nx1, nx2, nx3;
    XROW(0, cx0); XROW(1, cx1); XROW(2, cx2); XROW(3, cx3);
    SB();

#pragma unroll 1
    for (int q = 0; q < NPQ; ++q) {
        if (q + 2 < NPQ) STAGE(q + 2);
        SB();
        if (q + 1 < NPQ) {
            XROW(4*(q+1)+0, nx0); XROW(4*(q+1)+1, nx1);
            XROW(4*(q+1)+2, nx2); XROW(4*(q+1)+3, nx3);
        }
        SB();
        if (q < NPQ - 2)       { WAITV(5); }
        else if (q == NPQ - 2) { WAITV(4); }
        else                   { WAITV(0); }
        SB();
        ROW(q, 0, cx0); ROW(q, 1, cx1); ROW(q, 2, cx2); ROW(q, 3, cx3);
        cx0 = nx0; cx1 = nx1; cx2 = nx2; cx3 = nx3;
    }

    // cross-wave merge
    __syncthreads();
    float (*red)[DOUT + 1][NB] = reinterpret_cast<float (*)[DOUT + 1][NB]>(smem);
#pragma unroll
    for (int o = 0; o < DOUT; ++o) red[w][o][b] = S[o];
    red[w][DOUT][b] = Z;
    __syncthreads();
    for (int idx = threadIdx.x; idx < (DOUT + 1) * NB; idx += SWEEP_BLK) {
        const int slot = idx >> 6;
        const int bb   = idx & 63;
        float acc = 0.f;
#pragma unroll
        for (int k = 0; k < NW; ++k) acc += red[k][slot][bb];
        if (!WEIGHTED) {
            if (slot < DOUT)
                P[((size_t)bg * DOUT + slot) * NB + bb] = acc;
        } else {
            P[((size_t)bg * (DOUT + 1) + slot) * NB + bb] = acc;
        }
    }
}

// ================= fp32 fallback path (R9, proven) =================
__global__ __launch_bounds__(256) void prep_kernel(const float* __restrict__ x,
                                                   float* __restrict__ xs) {
    const int g = blockIdx.x * 256 + threadIdx.x;
    const int n = g >> 6;
    const int b = g & 63;
    const float4* xp = reinterpret_cast<const float4*>(x + ((size_t)b * NCAP + n) * DIN);
    float4 a = xp[0], c4 = xp[1];
    float sq = a.x*a.x + a.y*a.y + a.z*a.z + a.w*a.w
             + c4.x*c4.x + c4.y*c4.y + c4.z*c4.z + c4.w*c4.w;
    float sc = sq / ((1.0f + sq) * sqrtf(sq));
    float4 o0 = {a.x*sc,  a.y*sc,  a.z*sc,  a.w*sc};
    float4 o1 = {c4.x*sc, c4.y*sc, c4.z*sc, c4.w*sc};
    float4* op = reinterpret_cast<float4*>(xs + (size_t)g * DIN);
    op[0] = o0;
    op[1] = o1;
}

template<bool WEIGHTED, int CH>
__global__ __launch_bounds__(SWEEP_BLK, 2) void sweep_kernel(const float* __restrict__ xs,
                                                             const float* __restrict__ W,
                                                             float* __restrict__ P,
                                                             const float* __restrict__ vbuf) {
    constexpr int NPC    = NCAP / CH;
    constexpr int NPW    = NPC / NW;
    constexpr int NPAIRS = NPW / 2;

    const int bg = blockIdx.x;
    const int c  = bg / CH;
    const int ch = bg % CH;
    const int b  = threadIdx.x & 63;
    const int w  = threadIdx.x >> 6;

    __shared__ __align__(16) char smem[NW * (DOUT + 1) * NB * 4];

    float V[DOUT];
    if (WEIGHTED) {
        const float* vb = vbuf + (size_t)c * DOUT * NB + b;
#pragma unroll
        for (int o = 0; o < DOUT; ++o) V[o] = vb[o * NB];
    }

    float S[DOUT];
#pragma unroll
    for (int o = 0; o < DOUT; ++o) S[o] = 0.f;
    float Z = 0.f;

    const int n0 = ch * NPC + w * NPW;
    const char* wsrc = (const char*)W + ((size_t)c * NCAP + n0) * 512;
    char* mybuf = smem + w * STG;

    auto STAGE = [&](int p) {
        __builtin_amdgcn_global_load_lds(
            (const __attribute__((address_space(1))) void*)(wsrc + (size_t)p * 1024 + b * 16),
            (__attribute__((address_space(3))) void*)(mybuf + (p & 3) * 1024),
            16, 0, 0);
    };
    auto XROW = [&](int row, float4& xa, float4& xb) {
        const float4* xp = reinterpret_cast<const float4*>(
            xs + ((size_t)(n0 + row) * NB + b) * DIN);
        xa = xp[0];
        xb = xp[1];
    };
    auto ROW = [&](int p, int r, float4 xa, float4 xb) {
        const float4* wl = reinterpret_cast<const float4*>(mybuf + (p & 3) * 1024 + r * 512);
        const float xv[DIN] = {xa.x, xa.y, xa.z, xa.w, xb.x, xb.y, xb.z, xb.w};
        if (!WEIGHTED) {
#pragma unroll
            for (int i = 0; i < DIN; ++i) {
                float4 q0 = wl[i*4+0], q1 = wl[i*4+1], q2 = wl[i*4+2], q3 = wl[i*4+3];
                const float xi = xv[i];
                S[ 0]=fmaf(xi,q0.x,S[ 0]); S[ 1]=fmaf(xi,q0.y,S[ 1]);
                S[ 2]=fmaf(xi,q0.z,S[ 2]); S[ 3]=fmaf(xi,q0.w,S[ 3]);
                S[ 4]=fmaf(xi,q1.x,S[ 4]); S[ 5]=fmaf(xi,q1.y,S[ 5]);
                S[ 6]=fmaf(xi,q1.z,S[ 6]); S[ 7]=fmaf(xi,q1.w,S[ 7]);
                S[ 8]=fmaf(xi,q2.x,S[ 8]); S[ 9]=fmaf(xi,q2.y,S[ 9]);
                S[10]=fmaf(xi,q2.z,S[10]); S[11]=fmaf(xi,q2.w,S[11]);
                S[12]=fmaf(xi,q3.x,S[12]); S[13]=fmaf(xi,q3.y,S[13]);
                S[14]=fmaf(xi,q3.z,S[14]); S[15]=fmaf(xi,q3.w,S[15]);
            }
        } else {
            float u[DOUT];
#pragma unroll
            for (int o = 0; o < DOUT; ++o) u[o] = 0.f;
#pragma unroll
            for (int i = 0; i < DIN; ++i) {
                float4 q0 = wl[i*4+0], q1 = wl[i*4+1], q2 = wl[i*4+2], q3 = wl[i*4+3];
                const float xi = xv[i];
                u[ 0]=fmaf(xi,q0.x,u[ 0]); u[ 1]=fmaf(xi,q0.y,u[ 1]);
                u[ 2]=fmaf(xi,q0.z,u[ 2]); u[ 3]=fmaf(xi,q0.w,u[ 3]);
                u[ 4]=fmaf(xi,q1.x,u[ 4]); u[ 5]=fmaf(xi,q1.y,u[ 5]);
                u[ 6]=fmaf(xi,q1.z,u[ 6]); u[ 7]=fmaf(xi,q1.w,u[ 7]);
                u[ 8]=fmaf(xi,q2.x,u[ 8]); u[ 9]=fmaf(xi,q2.y,u[ 9]);
                u[10]=fmaf(xi,q2.z,u[10]); u[11]=fmaf(xi,q2.w,u[11]);
                u[12]=fmaf(xi,q3.x,u[12]); u[13]=fmaf(xi,q3.y,u[13]);
                u[14]=fmaf(xi,q3.z,u[14]); u[15]=fmaf(xi,q3.w,u[15]);
            }
            float bd = 0.f;
#pragma unroll
            for (int o = 0; o < DOUT; ++o) bd = fmaf(u[o], V[o], bd);
            const float g = __expf(bd);
            Z += g;
#pragma unroll
            for (int o = 0; o < DOUT; ++o) S[o] = fmaf(g, u[o], S[o]);
        }
    };

    STAGE(0); SB();
    STAGE(1); SB();
    float4 ca0, ca1, cb0, cb1, na0, na1, nb0, nb1;
    XROW(0, ca0, ca1);
    XROW(1, cb0, cb1);
    SB();

#pragma unroll 1
    for (int p = 0; p < NPAIRS; ++p) {
        if (p + 2 < NPAIRS) STAGE(p + 2);
        SB();
        if (p + 1 < NPAIRS) {
            XROW(2 * (p + 1),     na0, na1);
            XROW(2 * (p + 1) + 1, nb0, nb1);
        }
        SB();
        if (p < NPAIRS - 2)       { WAITV(5); }
        else if (p == NPAIRS - 2) { WAITV(4); }
        else                      { WAITV(0); }
        SB();
        ROW(p, 0, ca0, ca1);
        ROW(p, 1, cb0, cb1);
        ca0 = na0; ca1 = na1; cb0 = nb0; cb1 = nb1;
    }

    __syncthreads();
    float (*red)[DOUT + 1][NB] = reinterpret_cast<float (*)[DOUT + 1][NB]>(smem);
#pragma unroll
    for (int o = 0; o < DOUT; ++o) red[w][o][b] = S[o];
    red[w][DOUT][b] = Z;
    __syncthreads();
    for (int idx = threadIdx.x; idx < (DOUT + 1) * NB; idx += SWEEP_BLK) {
        const int slot = idx >> 6;
        const int bb   = idx & 63;
        float acc = 0.f;
#pragma unroll
        for (int k = 0; k < NW; ++k) acc += red[k][slot][bb];
        if (!WEIGHTED) {
            if (slot < DOUT)
                P[((size_t)bg * DOUT + slot) * NB + bb] = acc;
        } else {
            P[((size_t)bg * (DOUT + 1) + slot) * NB + bb] = acc;
        }
    }
}

// ---- vupd: merge partials -> V. MODE1: squash(sum/N). MODE2: vin + squash(S/Z).
template<int MODE, int CH>
__global__ __launch_bounds__(64) void vupd_kernel(const float* __restrict__ P,
                                                  const float* __restrict__ vin,
                                                  float* __restrict__ vout) {
    const int c = blockIdx.x;
    const int b = threadIdx.x;

    float s[DOUT];
    float sq = 0.f;
    if (MODE == 1) {
#pragma unroll
        for (int o = 0; o < DOUT; ++o) {
            float acc = 0.f;
#pragma unroll
            for (int k = 0; k < CH; ++k)
                acc += P[(((size_t)c * CH + k) * DOUT + o) * NB + b];
            acc *= (1.0f / (float)NCAP);
            s[o] = acc;
            sq += acc * acc;
        }
    } else {
        float Zt = 0.f;
#pragma unroll
        for (int k = 0; k < CH; ++k)
            Zt += P[(((size_t)c * CH + k) * (DOUT + 1) + DOUT) * NB + b];
        const float rz = 1.0f / Zt;
#pragma unroll
        for (int o = 0; o < DOUT; ++o) {
            float acc = 0.f;
#pragma unroll
            for (int k = 0; k < CH; ++k)
                acc += P[(((size_t)c * CH + k) * (DOUT + 1) + o) * NB + b];
            acc *= rz;
            s[o] = acc;
            sq += acc * acc;
        }
    }
    const float sc = sq / ((1.0f + sq) * sqrtf(sq));
#pragma unroll
    for (int o = 0; o < DOUT; ++o) {
        float v = s[o] * sc;
        if (MODE == 2) v += vin[((size_t)c * DOUT + o) * NB + b];
        vout[((size_t)c * DOUT + o) * NB + b] = v;
    }
}

// ---- final: merge P3 -> v3, leaky^2, per-batch normalize
template<int CH>
__global__ __launch_bounds__(256) void final_kernel(const float* __restrict__ P3,
                                                    float* __restrict__ out) {
    const int b    = blockIdx.x;
    const int tid  = threadIdx.x;
    const int c    = tid >> 1;
    const int half = tid & 1;

    float Zt = 0.f;
#pragma unroll
    for (int k = 0; k < CH; ++k)
        Zt += P3[(((size_t)c * CH + k) * (DOUT + 1) + DOUT) * NB + b];
    const float rz = 1.0f / Zt;

    float s[8];
    float sqh = 0.f;
#pragma unroll
    for (int j = 0; j < 8; ++j) {
        const int o = half * 8 + j;
        float acc = 0.f;
#pragma unroll
        for (int k = 0; k < CH; ++k)
            acc += P3[(((size_t)c * CH + k) * (DOUT + 1) + o) * NB + b];
        acc *= rz;
        s[j] = acc;
        sqh += acc * acc;
    }
    const float sq = sqh + __shfl_xor(sqh, 1);
    const float sc = sq / ((1.0f + sq) * sqrtf(sq));

    float val[8];
    float ps = 0.f;
#pragma unroll
    for (int j = 0; j < 8; ++j) {
        const float v = s[j] * sc;
        const float l = v > 0.f ? v : 0.01f * v;
        val[j] = l * l;
        ps += val[j];
    }
#pragma unroll
    for (int off = 1; off < 64; off <<= 1) ps += __shfl_xor(ps, off);
    __shared__ float wsum[4];
    if ((tid & 63) == 0) wsum[tid >> 6] = ps;
    __syncthreads();
    const float inv = 1.0f / (wsum[0] + wsum[1] + wsum[2] + wsum[3]);
#pragma unroll
    for (int j = 0; j < 8; ++j)
        out[((size_t)b * NCLS + c) * DOUT + half * 8 + j] = val[j] * inv;
}

template<int CH>
static void run_f32(const float* x, const float* W, float* out, float* ws,
                    hipStream_t stream) {
    using L = Layout<CH>;
    float* xs = ws + L::XS_OFF;
    float* P1 = ws + L::P1_OFF;
    float* P2 = ws + L::P2_OFF;
    float* P3 = ws + L::P3_OFF;
    float* VA = ws + L::VA_OFF;
    float* VB = ws + L::VB_OFF;

    hipLaunchKernelGGL(prep_kernel, dim3(NCAP * NB / 256), dim3(256), 0, stream, x, xs);
    hipLaunchKernelGGL((sweep_kernel<false, CH>), dim3(NCLS * CH), dim3(SWEEP_BLK), 0,
                       stream, xs, W, P1, nullptr);
    hipLaunchKernelGGL((vupd_kernel<1, CH>), dim3(NCLS), dim3(64), 0, stream,
                       P1, nullptr, VA);
    hipLaunchKernelGGL((sweep_kernel<true, CH>), dim3(NCLS * CH), dim3(SWEEP_BLK), 0,
                       stream, xs, W, P2, VA);
    hipLaunchKernelGGL((vupd_kernel<2, CH>), dim3(NCLS), dim3(64), 0, stream,
                       P2, VA, VB);
    hipLaunchKernelGGL((sweep_kernel<true, CH>), dim3(NCLS * CH), dim3(SWEEP_BLK), 0,
                       stream, xs, W, P3, VB);
    hipLaunchKernelGGL((final_kernel<CH>), dim3(NB), dim3(256), 0, stream, P3, out);
}

extern "C" void kernel_launch(void* const* d_in, const int* in_sizes, int n_in,
                              void* d_out, int out_size, void* d_ws, size_t ws_size,
                              hipStream_t stream) {
    const float* x = (const float*)d_in[0];
    const float* W = (const float*)d_in[1];
    float* out = (float*)d_out;
    float* ws  = (float*)d_ws;

    if (ws_size >= L16::TOTAL * sizeof(float)) {
        constexpr int CH = L16::CH;
        float* xsh = ws + L16::XSH_OFF;
        float* wh  = ws + L16::WH_OFF;
        float* P1  = ws + L16::P1_OFF;
        float* P2  = ws + L16::P2_OFF;
        float* P3  = ws + L16::P3_OFF;
        float* VA  = ws + L16::VA_OFF;
        float* VB  = ws + L16::VB_OFF;

        hipLaunchKernelGGL(prep_x, dim3(NCAP * NB / 256), dim3(256), 0, stream, x, xsh);
        hipLaunchKernelGGL(prep_w, dim3(NCLS * NCAP * 4 / 256), dim3(256), 0, stream, W, wh);
        hipLaunchKernelGGL((sweep_h<false>), dim3(NCLS * CH), dim3(SWEEP_BLK), 0,
                           stream, xsh, wh, P1, nullptr);
        hipLaunchKernelGGL((vupd_kernel<1, CH>), dim3(NCLS), dim3(64), 0, stream,
                           P1, nullptr, VA);
        hipLaunchKernelGGL((sweep_h<true>), dim3(NCLS * CH), dim3(SWEEP_BLK), 0,
                           stream, xsh, wh, P2, VA);
        hipLaunchKernelGGL((vupd_kernel<2, CH>), dim3(NCLS), dim3(64), 0, stream,
                           P2, VA, VB);
        hipLaunchKernelGGL((sweep_h<true>), dim3(NCLS * CH), dim3(SWEEP_BLK), 0,
                           stream, xsh, wh, P3, VB);
        hipLaunchKernelGGL((final_kernel<CH>), dim3(NB), dim3(256), 0, stream, P3, out);
    } else if (ws_size >= Layout<8>::TOTAL * sizeof(float)) {
        run_f32<8>(x, W, out, ws, stream);
    } else {
        run_f32<4>(x, W, out, ws, stream);
    }
}